// Round 13
// baseline (485.582 us; speedup 1.0000x reference)
//
#include <hip/hip_runtime.h>
#include <hip/hip_bf16.h>
#include <stdint.h>

#define N_NODES 50000
#define N_EDGES 800000
#define NL 2

// K strides (bf16 elements)
#define KS2 136   // 128-K GEMMs: 4 k-steps, stride 136
#define KSU 264   // upd GEMM1: K=256 (8 k-steps), stride 264
// edge_kernel fp32 LDS stride (dwords): 132 -> 528B rows, 16B-aligned (b128-capable).
// NOTE (R6 post-mortem): do NOT remap P2 gathers to 128B/row contiguous form —
// full-line random requests thrash L2 (aggr dirty-evictions: WRITE 31->118MB,
// dur 66->72us). The 32B-interleaved mapping below is the measured optimum.
// NOTE (R11 post-mortem): residual trunk MUST stay fp32 (bf16 residual -> absmax
// 0.06-0.125 vs threshold 0.09875; LN amplifies the rounding). h is fp32; the
// residual rides in registers between upd's staging and LN phases.
#define ESTR 132

typedef __bf16 bf16x8 __attribute__((ext_vector_type(8)));
typedef float f32x4 __attribute__((ext_vector_type(4)));

__device__ __forceinline__ f32x4 mfma_bf16(uint4 a, uint4 b, f32x4 c) {
    return __builtin_amdgcn_mfma_f32_16x16x32_bf16(
        __builtin_bit_cast(bf16x8, a), __builtin_bit_cast(bf16x8, b), c, 0, 0, 0);
}

__device__ __forceinline__ unsigned short f2b(float f) {
    union { float f; unsigned u; } v; v.f = f;
    unsigned r = v.u + 0x7FFFu + ((v.u >> 16) & 1u);   // RNE
    return (unsigned short)(r >> 16);
}

__device__ __forceinline__ float b2f_lo(unsigned u) {
    union { unsigned u; float f; } v; v.u = u << 16; return v.f;
}
__device__ __forceinline__ float b2f_hi(unsigned u) {
    union { unsigned u; float f; } v; v.u = u & 0xFFFF0000u; return v.f;
}
__device__ __forceinline__ unsigned pk2(unsigned short a, unsigned short b) {
    return (unsigned)a | ((unsigned)b << 16);
}

// RT row-tiles x 1 col-tile per wave.
template<int RT, int KSTEPS, int ASTR, int BSTR>
__device__ __forceinline__ void gemm_1xR(const unsigned short* aLane,
                                         const unsigned short* bLane,
                                         f32x4 acc[RT]) {
#pragma unroll
    for (int kc = 0; kc < KSTEPS; kc++) {
        uint4 b0 = *(const uint4*)(bLane + kc * 32);
#pragma unroll
        for (int rt = 0; rt < RT; rt++) {
            uint4 a = *(const uint4*)(aLane + (size_t)rt * 16 * ASTR + kc * 32);
            acc[rt] = mfma_bf16(a, b0, acc[rt]);
        }
    }
}

// RT row-tiles x 2 col-tiles per wave.
template<int RT, int KSTEPS, int ASTR, int BSTR>
__device__ __forceinline__ void gemm_2xR(const unsigned short* aLane,
                                         const unsigned short* bLane,
                                         f32x4 acc[RT][2]) {
#pragma unroll
    for (int kc = 0; kc < KSTEPS; kc++) {
        uint4 b0 = *(const uint4*)(bLane + kc * 32);
        uint4 b1 = *(const uint4*)(bLane + (size_t)16 * BSTR + kc * 32);
#pragma unroll
        for (int rt = 0; rt < RT; rt++) {
            uint4 a = *(const uint4*)(aLane + (size_t)rt * 16 * ASTR + kc * 32);
            acc[rt][0] = mfma_bf16(a, b0, acc[rt][0]);
            acc[rt][1] = mfma_bf16(a, b1, acc[rt][1]);
        }
    }
}

// ---------------- weight prep ----------------
__global__ void prep_kernel(const float* __restrict__ mW1,
                            const float* __restrict__ uW1, const float* __restrict__ uW2,
                            const float* __restrict__ hW,
                            unsigned short* __restrict__ wab, unsigned short* __restrict__ w1cp,
                            unsigned short* __restrict__ u1t, unsigned short* __restrict__ u2t,
                            unsigned short* __restrict__ ht) {
    int i = blockIdx.x * 256 + threadIdx.x;
    const int SA = NL * 256 * 136;
    const int SC = NL * 128 * 32;
    const int SU = NL * 128 * KSU;
    const int S3 = NL * 128 * KS2;
    const int S4 = 128 * KS2;
    if (i < SA) {
        int l = i / (256 * 136), r = i % (256 * 136), j = r / 136, k = r % 136;
        float v = 0.f;
        if (k < 128)
            v = (j < 128) ? mW1[((size_t)l * 272 + k) * 128 + j]
                          : mW1[((size_t)l * 272 + 128 + k) * 128 + (j - 128)];
        wab[i] = f2b(v);
        return;
    }
    i -= SA;
    if (i < SC) {
        int l = i / (128 * 32), r = i % (128 * 32), j = r / 32, k = r % 32;
        w1cp[i] = (k < 16) ? f2b(mW1[((size_t)l * 272 + 256 + k) * 128 + j]) : (unsigned short)0;
        return;
    }
    i -= SC;
    if (i < SU) {
        int l = i / (128 * KSU), r = i % (128 * KSU), n = r / KSU, k = r % KSU;
        if (k < 128)       u1t[i] = f2b(uW1[((size_t)l * 256 + k) * 128 + n]);
        else if (k >= 256) u1t[i] = 0;
        return;
    }
    i -= SU;
    if (i < S3) {
        int l = i / (128 * KS2), r = i % (128 * KS2), n = r / KS2, k = r % KS2;
        u2t[i] = (k < 128) ? f2b(uW2[((size_t)l * 128 + k) * 128 + n]) : (unsigned short)0;
        return;
    }
    i -= S3;
    if (i < S4) {
        int n = i / KS2, k = i % KS2;
        ht[i] = (k < 128) ? f2b(hW[(size_t)k * 128 + n]) : (unsigned short)0;
    }
}

// ---------------- prep2: u1t[l][n][128+j] = bf16( sum_c W2[l][j][c] * U1[l][128+c][n] )
__global__ void prep2_kernel(const float* __restrict__ mW2, const float* __restrict__ uW1,
                             unsigned short* __restrict__ u1t) {
    __shared__ float w2row[128];
    const int l = blockIdx.x >> 7, j = blockIdx.x & 127;
    const int n = threadIdx.x;
    w2row[n] = mW2[((size_t)l * 128 + j) * 128 + n];
    __syncthreads();
    float s = 0.f;
#pragma unroll 8
    for (int c = 0; c < 128; c++)
        s += w2row[c] * uW1[((size_t)l * 256 + 128 + c) * 128 + n];
    u1t[(size_t)l * 128 * KSU + (size_t)n * KSU + 128 + j] = f2b(s);
}

// ---------------- prep3: bfold[l][n] = sum_c b2[l][c] * U1[l][128+c][n]
__global__ void prep3_kernel(const float* __restrict__ mb2, const float* __restrict__ uW1,
                             float* __restrict__ bfold) {
    const int l = blockIdx.x;
    const int n = threadIdx.x;
    float s = 0.f;
#pragma unroll 8
    for (int c = 0; c < 128; c++)
        s += mb2[l * 128 + c] * uW1[((size_t)l * 256 + 128 + c) * 128 + n];
    bfold[l * 128 + n] = s;
}

// ---------------- fused encoder + layer-0 node GEMM ----------------
// 32 nodes/block, 512 threads, 1563 blocks.
__global__ __launch_bounds__(512, 8) void encnode_kernel(
        const float* __restrict__ x, const float* __restrict__ W,
        const float* __restrict__ b, const float* __restrict__ g, const float* __restrict__ bet,
        const unsigned short* __restrict__ wab, const float* __restrict__ b1,
        float* __restrict__ h,
        unsigned short* __restrict__ Tb, unsigned short* __restrict__ Sb) {
    __shared__ __align__(16) unsigned short Ah[32 * KS2];   // 8704 B
    __shared__ float xs[32 * 33];                           // 4224 B
    __shared__ __align__(16) float Ws[32 * 128];            // 16384 B
    const int t = threadIdx.x;
    const int n0 = blockIdx.x * 32;

    {   // stage x: 16 threads/row, float2 each (row stride 33)
        const int m = t >> 4, q = t & 15;
        const int nd = n0 + m;
        float2 v = {0.f, 0.f};
        if (nd < N_NODES) v = *(const float2*)(x + (size_t)nd * 32 + q * 2);
        xs[m * 33 + q * 2 + 0] = v.x;
        xs[m * 33 + q * 2 + 1] = v.y;
    }
    {   // stage W [32][128] f32
        const float4* s = (const float4*)W;
        float4* d = (float4*)Ws;
        d[t * 2] = s[t * 2];
        d[t * 2 + 1] = s[t * 2 + 1];
    }
    __syncthreads();

    const int r = t >> 4, q16 = t & 15;
    const int node = n0 + r;
    const bool valid = (node < N_NODES);

    // Phase A: cols c = q16 + 16j, j<8
    float vbuf[8];
#pragma unroll
    for (int j = 0; j < 8; j++) vbuf[j] = b[q16 + 16 * j];
    for (int k = 0; k < 32; k++) {
        const float xv = xs[r * 33 + k];
#pragma unroll
        for (int j = 0; j < 8; j++)
            vbuf[j] += xv * Ws[k * 128 + q16 + 16 * j];
    }
#pragma unroll
    for (int j = 0; j < 8; j++) vbuf[j] = fmaxf(vbuf[j], 0.f);

    // Phase B: LN over row r (16 lanes/row); write h fp32 + Ah bf16
    {
        float s = 0.f, ss = 0.f;
#pragma unroll
        for (int j = 0; j < 8; j++) { s += vbuf[j]; ss += vbuf[j] * vbuf[j]; }
        s += __shfl_xor(s, 1); ss += __shfl_xor(ss, 1);
        s += __shfl_xor(s, 2); ss += __shfl_xor(ss, 2);
        s += __shfl_xor(s, 4); ss += __shfl_xor(ss, 4);
        s += __shfl_xor(s, 8); ss += __shfl_xor(ss, 8);
        const float mu = s * (1.0f / 128.0f);
        const float var = ss * (1.0f / 128.0f) - mu * mu;
        const float rs = rsqrtf(var + 1e-5f);
#pragma unroll
        for (int j = 0; j < 8; j++) {
            const int col = q16 + 16 * j;
            const float v = (vbuf[j] - mu) * rs * g[col] + bet[col];
            Ah[r * KS2 + col] = valid ? f2b(v) : (unsigned short)0;
            if (valid) h[(size_t)node * 128 + col] = v;
        }
    }
    __syncthreads();

    // Phase C: node l=0 GEMM epilogue (32 rows x 32 cols per wave)
    const int wv = t >> 6, lane = t & 63, lr = lane & 15, lq = lane >> 4;
    const int cbn = wv * 32;
    const f32x4 z4 = {0.f, 0.f, 0.f, 0.f};
    f32x4 accn[2][2];
#pragma unroll
    for (int i = 0; i < 2; i++) { accn[i][0] = z4; accn[i][1] = z4; }
    gemm_2xR<2, 4, KS2, KS2>(Ah + lr * KS2 + lq * 8,
                             wab + (size_t)(cbn + lr) * KS2 + lq * 8, accn);
#pragma unroll
    for (int ct = 0; ct < 2; ct++) {
        const int j = cbn + ct * 16 + lr;
        const float bias = (j < 128) ? b1[j] : 0.f;
#pragma unroll
        for (int rt = 0; rt < 2; rt++) {
#pragma unroll
            for (int r2 = 0; r2 < 4; r2++) {
                const int node2 = n0 + rt * 16 + lq * 4 + r2;
                if (node2 < N_NODES) {
                    const float v = accn[rt][ct][r2] + bias;
                    if (j < 128) Tb[(size_t)node2 * 128 + j] = f2b(v);
                    else         Sb[(size_t)node2 * 128 + (j - 128)] = f2b(v);
                }
            }
        }
    }
}

// ---------------- counting sort of edges by target ----------------
__global__ void hist_kernel(const int* __restrict__ tgt, int* __restrict__ hist) {
    int i = blockIdx.x * 256 + threadIdx.x;   // E = 3125*256 exact
    atomicAdd(hist + tgt[i], 1);
}

__global__ void scan1_kernel(const int* __restrict__ hist, int* __restrict__ incl,
                             int* __restrict__ blksum) {
    __shared__ int buf[256];
    const int t = threadIdx.x;
    const int i = blockIdx.x * 256 + t;
    int v = (i < N_NODES) ? hist[i] : 0;
    buf[t] = v; __syncthreads();
#pragma unroll
    for (int d = 1; d < 256; d <<= 1) {
        int x = (t >= d) ? buf[t - d] : 0;
        __syncthreads();
        buf[t] += x;
        __syncthreads();
    }
    if (i < N_NODES) incl[i] = buf[t];
    if (t == 255) blksum[blockIdx.x] = buf[255];
}

__global__ void scan2_kernel(int* __restrict__ blksum, int nblk) {
    __shared__ int buf[256];
    const int t = threadIdx.x;
    int v = (t < nblk) ? blksum[t] : 0;
    buf[t] = v; __syncthreads();
#pragma unroll
    for (int d = 1; d < 256; d <<= 1) {
        int x = (t >= d) ? buf[t - d] : 0;
        __syncthreads();
        buf[t] += x;
        __syncthreads();
    }
    if (t < nblk) blksum[t] = buf[t];
}

__global__ void scan3_kernel(int* __restrict__ incl, const int* __restrict__ blksum,
                             const int* __restrict__ hist) {
    const int i = blockIdx.x * 256 + threadIdx.x;
    if (i >= N_NODES) return;
    const int b = blockIdx.x;
    const int base = (b > 0) ? blksum[b - 1] : 0;
    incl[i] = incl[i] + base - hist[i];
}

// ---------------- sort step 1: 8B random scatter of {edge id, packed src|tgt} ------
__global__ void scatterp_kernel(const int* __restrict__ src, const int* __restrict__ tgt,
                                int* __restrict__ cursor, uint2* __restrict__ permst) {
    const int e = blockIdx.x * 256 + threadIdx.x;   // E exact
    const int tg = tgt[e];
    const int p = atomicAdd(cursor + tg, 1);
    permst[p] = make_uint2((unsigned)e, ((unsigned)src[e] << 16) | (unsigned)tg);
}

// ---------------- sort step 2: coalesced gather + bf16 convert --------------------
__global__ __launch_bounds__(256) void gather_kernel(
        const uint2* __restrict__ permst, const float* __restrict__ ea,
        unsigned int* __restrict__ sST, unsigned short* __restrict__ eabS) {
    const int p = blockIdx.x * 256 + threadIdx.x;   // E exact
    const uint2 v = permst[p];
    sST[p] = v.y;
    const float4* s = (const float4*)(ea + (size_t)v.x * 16);
    ushort4* d = (ushort4*)(eabS + (size_t)p * 16);
#pragma unroll
    for (int i = 0; i < 4; i++) {
        float4 f = s[i];
        d[i] = make_ushort4(f2b(f.x), f2b(f.y), f2b(f.z), f2b(f.w));
    }
}

// ---------------- edge kernel: relu(T[tgt]+S[src]+ea@W1c) + segmented sum ----------------
// 64 edges/block as two 32-edge half-tiles over one fp32 LDS buffer Es[32][ESTR=132]
// (17.4 KB LDS -> 8 blocks/CU). R5-measured optimum: 66us, 0 bank conflicts.
// R13: XCD-chunked block swizzle (T1). Edges are target-sorted, so contiguous
// blocks share Tb/aggr rows; default round-robin XCD assignment spreads neighbors
// across 8 non-coherent L2s (each XCD streams ~all of Tb's 12.8MB). Chunked
// bijective mapping (4 chunks of 1563 + 4 of 1562 = 12500) gives each XCD a
// contiguous ~6250-target range -> Tb slice ~1.6MB, L2-resident.
__global__ __launch_bounds__(256, 8) void edge_kernel(
        const unsigned short* __restrict__ eabS,
        const unsigned int* __restrict__ sST,
        const unsigned short* __restrict__ w1cp,
        const unsigned short* __restrict__ Tb, const unsigned short* __restrict__ Sb,
        float* __restrict__ aggr) {
    __shared__ __align__(16) float Es[32 * ESTR];
    __shared__ int sT[64];
    __shared__ int sS[64];

    const int t = threadIdx.x;
    int bid;
    {   // bijective XCD-chunked swizzle: nwg=12500, q=1562, r=4
        const int q = 1562, rr = 4;
        const int xcd = blockIdx.x & 7, pos = blockIdx.x >> 3;
        bid = ((xcd < rr) ? xcd * (q + 1) : rr * (q + 1) + (xcd - rr) * q) + pos;
    }
    const int e0 = bid * 64;                 // E = 12500*64 exact
    if (t < 64) {
        const unsigned v = sST[e0 + t];
        sT[t] = (int)(v & 0xFFFFu);
        sS[t] = (int)(v >> 16);
    }
    __syncthreads();                         // A: sT/sS visible

    const int wv = t >> 6, lane = t & 63, lr = lane & 15, lq = lane >> 4;
    const int rtw = (wv >> 1) * 16;          // row-tile base within half: 0 or 16
    const int cbw = (wv & 1) * 64;           // col-block base: 0 or 64
    const int m = t & 31, c8b = t >> 5;      // P2 mapping: edge-in-half, col chunk
    const f32x4 z4 = {0.f, 0.f, 0.f, 0.f};

    // boundary ballot (wave-uniform SGPR mask, same in all waves)
    unsigned long long bmask;
    {
        const int l = t & 63;
        const int a = sT[l];
        const int b = (l > 0) ? sT[l - 1] : a;
        bmask = __ballot(a != b);
    }

    // ---- issue half-0 gathers (consumed in P2 h0; hidden under P1 h0) ----
    uint4 t0a, t0b, s0a, s0b;
    {
        const unsigned short* Tr = Tb + (size_t)sT[m] * 128;
        const unsigned short* Sr = Sb + (size_t)sS[m] * 128;
        t0a = *(const uint4*)(Tr + c8b * 8);
        t0b = *(const uint4*)(Tr + c8b * 8 + 64);
        s0a = *(const uint4*)(Sr + c8b * 8);
        s0b = *(const uint4*)(Sr + c8b * 8 + 64);
    }

    float s = 0.f;                           // P3 running segment sum (t<128)
    bool first = true;                       // first flush -> atomic; interior -> store

    {   // ---- P1 h0 ----
        uint4 a = {0, 0, 0, 0};
        if (lq < 2)
            a = *(const uint4*)(eabS + (size_t)(e0 + rtw + lr) * 16 + lq * 8);
        f32x4 acc[4];
#pragma unroll
        for (int ct = 0; ct < 4; ct++) {
            uint4 b = *(const uint4*)(w1cp + (cbw + ct * 16 + lr) * 32 + lq * 8);
            acc[ct] = mfma_bf16(a, b, z4);
        }
#pragma unroll
        for (int ct = 0; ct < 4; ct++) {
            const int col = cbw + ct * 16 + lr;
#pragma unroll
            for (int r = 0; r < 4; r++)
                Es[(rtw + lq * 4 + r) * ESTR + col] = acc[ct][r];
        }
    }
    __syncthreads();                         // B

    uint4 t1a, t1b, s1a, s1b;
    {   // ---- P2 h0: consume prefetch, float4 RMW ----
        float* Erow = Es + m * ESTR;
        float4* EA = (float4*)(Erow + c8b * 8);
        float4* EB = (float4*)(Erow + c8b * 8 + 64);
        float4 ea0 = EA[0], ea1 = EA[1];
        ea0.x = fmaxf(ea0.x + b2f_lo(t0a.x) + b2f_lo(s0a.x), 0.f);
        ea0.y = fmaxf(ea0.y + b2f_hi(t0a.x) + b2f_hi(s0a.x), 0.f);
        ea0.z = fmaxf(ea0.z + b2f_lo(t0a.y) + b2f_lo(s0a.y), 0.f);
        ea0.w = fmaxf(ea0.w + b2f_hi(t0a.y) + b2f_hi(s0a.y), 0.f);
        ea1.x = fmaxf(ea1.x + b2f_lo(t0a.z) + b2f_lo(s0a.z), 0.f);
        ea1.y = fmaxf(ea1.y + b2f_hi(t0a.z) + b2f_hi(s0a.z), 0.f);
        ea1.z = fmaxf(ea1.z + b2f_lo(t0a.w) + b2f_lo(s0a.w), 0.f);
        ea1.w = fmaxf(ea1.w + b2f_hi(t0a.w) + b2f_hi(s0a.w), 0.f);
        EA[0] = ea0; EA[1] = ea1;
        float4 eb0 = EB[0], eb1 = EB[1];
        eb0.x = fmaxf(eb0.x + b2f_lo(t0b.x) + b2f_lo(s0b.x), 0.f);
        eb0.y = fmaxf(eb0.y + b2f_hi(t0b.x) + b2f_hi(s0b.x), 0.f);
        eb0.z = fmaxf(eb0.z + b2f_lo(t0b.y) + b2f_lo(s0b.y), 0.f);
        eb0.w = fmaxf(eb0.w + b2f_hi(t0b.y) + b2f_hi(s0b.y), 0.f);
        eb1.x = fmaxf(eb1.x + b2f_lo(t0b.z) + b2f_lo(s0b.z), 0.f);
        eb1.y = fmaxf(eb1.y + b2f_hi(t0b.z) + b2f_hi(s0b.z), 0.f);
        eb1.z = fmaxf(eb1.z + b2f_lo(t0b.w) + b2f_lo(s0b.w), 0.f);
        eb1.w = fmaxf(eb1.w + b2f_hi(t0b.w) + b2f_hi(s0b.w), 0.f);
        EB[0] = eb0; EB[1] = eb1;

        // ---- issue half-1 gathers (consumed in P2 h1; hidden under P3 h0 + P1 h1)
        const unsigned short* Tr = Tb + (size_t)sT[32 + m] * 128;
        const unsigned short* Sr = Sb + (size_t)sS[32 + m] * 128;
        t1a = *(const uint4*)(Tr + c8b * 8);
        t1b = *(const uint4*)(Tr + c8b * 8 + 64);
        s1a = *(const uint4*)(Sr + c8b * 8);
        s1b = *(const uint4*)(Sr + c8b * 8 + 64);
    }
    __syncthreads();                         // C

    if (t < 128) {   // ---- P3 h0: col c = t, rows 0..31, batched loads ----
        const int c = t;
        const unsigned mh = (unsigned)bmask;
#pragma unroll
        for (int i8 = 0; i8 < 4; i8++) {
            float v[8];
#pragma unroll
            for (int j = 0; j < 8; j++) v[j] = Es[(i8 * 8 + j) * ESTR + c];
#pragma unroll
            for (int j = 0; j < 8; j++) {
                const int i = i8 * 8 + j;
                if (mh & (1u << i)) {        // wave-uniform scalar branch
                    float* dst = aggr + (size_t)sT[i - 1] * 128 + c;
                    if (first) { atomicAdd(dst, s); first = false; }
                    else       { *dst = s; }
                    s = 0.f;
                }
                s += v[j];
            }
        }
    }
    __syncthreads();                         // D: Es free for h1

    {   // ---- P1 h1 ----
        uint4 a = {0, 0, 0, 0};
        if (lq < 2)
            a = *(const uint4*)(eabS + (size_t)(e0 + 32 + rtw + lr) * 16 + lq * 8);
        f32x4 acc[4];
#pragma unroll
        for (int ct = 0; ct < 4; ct++) {
            uint4 b = *(const uint4*)(w1cp + (cbw + ct * 16 + lr) * 32 + lq * 8);
            acc[ct] = mfma_bf16(a, b, z4);
        }
#pragma unroll
        for (int ct = 0; ct < 4; ct++) {
            const int col = cbw + ct * 16 + lr;
#pragma unroll
            for (int r = 0; r < 4; r++)
                Es[(rtw + lq * 4 + r) * ESTR + col] = acc[ct][r];
        }
    }
    __syncthreads();                         // E

    {   // ---- P2 h1 ----
        float* Erow = Es + m * ESTR;
        float4* EA = (float4*)(Erow + c8b * 8);
        float4* EB = (float4*)(Erow + c8b * 8 + 64);
        float4 ea0 = EA[0], ea1 = EA[1];
        ea0.x = fmaxf(ea0.x + b2f_lo(t1a.x) + b2f_lo(s1a.x), 0.f);
        ea0.y = fmaxf(ea0.y + b2f_hi(t1a.x) + b2f_hi(s1a.x), 0.f);
        ea0.z = fmaxf(ea0.z + b2f_lo(t1a.y) + b2f_lo(s1a.y), 0.f);
        ea0.w = fmaxf(ea0.w + b2f_hi(t1a.y) + b2f_hi(s1a.y), 0.f);
        ea1.x = fmaxf(ea1.x + b2f_lo(t1a.z) + b2f_lo(s1a.z), 0.f);
        ea1.y = fmaxf(ea1.y + b2f_hi(t1a.z) + b2f_hi(s1a.z), 0.f);
        ea1.z = fmaxf(ea1.z + b2f_lo(t1a.w) + b2f_lo(s1a.w), 0.f);
        ea1.w = fmaxf(ea1.w + b2f_hi(t1a.w) + b2f_hi(s1a.w), 0.f);
        EA[0] = ea0; EA[1] = ea1;
        float4 eb0 = EB[0], eb1 = EB[1];
        eb0.x = fmaxf(eb0.x + b2f_lo(t1b.x) + b2f_lo(s1b.x), 0.f);
        eb0.y = fmaxf(eb0.y + b2f_hi(t1b.x) + b2f_hi(s1b.x), 0.f);
        eb0.z = fmaxf(eb0.z + b2f_lo(t1b.y) + b2f_lo(s1b.y), 0.f);
        eb0.w = fmaxf(eb0.w + b2f_hi(t1b.y) + b2f_hi(s1b.y), 0.f);
        eb1.x = fmaxf(eb1.x + b2f_lo(t1b.z) + b2f_lo(s1b.z), 0.f);
        eb1.y = fmaxf(eb1.y + b2f_hi(t1b.z) + b2f_hi(s1b.z), 0.f);
        eb1.z = fmaxf(eb1.z + b2f_lo(t1b.w) + b2f_lo(s1b.w), 0.f);
        eb1.w = fmaxf(eb1.w + b2f_hi(t1b.w) + b2f_hi(s1b.w), 0.f);
        EB[0] = eb0; EB[1] = eb1;
    }
    __syncthreads();                         // F

    if (t < 128) {   // ---- P3 h1: rows 32..63 ----
        const int c = t;
        const unsigned mh = (unsigned)(bmask >> 32);
#pragma unroll
        for (int i8 = 0; i8 < 4; i8++) {
            float v[8];
#pragma unroll
            for (int j = 0; j < 8; j++) v[j] = Es[(i8 * 8 + j) * ESTR + c];
#pragma unroll
            for (int j = 0; j < 8; j++) {
                const int i = i8 * 8 + j;
                if (mh & (1u << i)) {
                    float* dst = aggr + (size_t)sT[32 + i - 1] * 128 + c;
                    if (first) { atomicAdd(dst, s); first = false; }
                    else       { *dst = s; }
                    s = 0.f;
                }
                s += v[j];
            }
        }
        atomicAdd(aggr + (size_t)sT[63] * 128 + c, s);   // may span blocks
    }
}

// ---------------- update MLP + residual(fp32, register-carried) + LN + epilogue ----
// 32 nodes/block, 512 threads, 1563 blocks. The fp32 residual rides in hrv[8]
// registers (staging thread slice == LN thread slice).
// mode==2 (layer 0): epilogue = next layer's node GEMM + h fp32 write-back.
// mode==1 (last layer): epilogue = head GEMM -> out.
__global__ __launch_bounds__(512, 8) void upd_kernel(
        const float* __restrict__ h_in,
        const float* __restrict__ aggr, const int* __restrict__ hist,
        const unsigned short* __restrict__ u1t, const unsigned short* __restrict__ u2t,
        const float* __restrict__ b1, const float* __restrict__ bf,
        const float* __restrict__ b2,
        const float* __restrict__ g, const float* __restrict__ bet,
        float* __restrict__ h_out,
        const unsigned short* __restrict__ wabn, const float* __restrict__ b1n,
        unsigned short* __restrict__ Tb, unsigned short* __restrict__ Sb,
        const unsigned short* __restrict__ ht, const float* __restrict__ hbias,
        float* __restrict__ out, const int mode) {
    __shared__ __align__(16) char smemA[32 * KSU * 2];   // 16896 B
    __shared__ float sF[32];
    unsigned short* As = (unsigned short*)smemA;
    float* LNb = (float*)smemA;                          // [32][132] fp32, same span

    const int t = threadIdx.x;
    const int n0 = blockIdx.x * 32;
    float hrv[8];                            // fp32 residual, staging -> LN phase
#pragma unroll
    for (int i = 0; i < 8; i++) hrv[i] = 0.f;
    {
        const int m = t >> 4, q = t & 15;    // 16 threads per row
        const int node = n0 + m;
        unsigned short* row = As + m * KSU;
        if (node < N_NODES) {
            const float4* ph = (const float4*)(h_in + (size_t)node * 128 + q * 8);
            const float4 h0 = ph[0], h1 = ph[1];
            hrv[0] = h0.x; hrv[1] = h0.y; hrv[2] = h0.z; hrv[3] = h0.w;
            hrv[4] = h1.x; hrv[5] = h1.y; hrv[6] = h1.z; hrv[7] = h1.w;
            ((uint4*)(row + q * 8))[0] =
                make_uint4(pk2(f2b(hrv[0]), f2b(hrv[1])), pk2(f2b(hrv[2]), f2b(hrv[3])),
                           pk2(f2b(hrv[4]), f2b(hrv[5])), pk2(f2b(hrv[6]), f2b(hrv[7])));
            const int cntv = hist[node];
            if (q == 0) sF[m] = (cntv > 0) ? 1.f : 0.f;
            const float rden = 1.0f / fmaxf((float)cntv, 1.0f);
            const float4* pa = (const float4*)(aggr + (size_t)node * 128 + q * 8);
            ushort4* d1 = (ushort4*)(row + 128 + q * 8);
#pragma unroll
            for (int i = 0; i < 2; i++) {
                float4 v = pa[i];
                d1[i] = make_ushort4(f2b(v.x * rden), f2b(v.y * rden),
                                     f2b(v.z * rden), f2b(v.w * rden));
            }
            if (q == 0) { uint4 z{0, 0, 0, 0}; ((uint4*)(row + 256))[0] = z; }
        } else {
            if (q == 0) sF[m] = 0.f;
            uint4 z{0, 0, 0, 0};
            uint4* d = (uint4*)row;
            for (int i = q; i < 33; i += 16) d[i] = z;
        }
    }
    __syncthreads();

    const int wv = t >> 6, lane = t & 63, lr = lane & 15, lq = lane >> 4;
    const int cb16 = wv * 16;                // 16 cols per wave (8 waves x 16 = 128)
    const f32x4 z4 = {0.f, 0.f, 0.f, 0.f};

    f32x4 acc[2];
    acc[0] = z4; acc[1] = z4;
    gemm_1xR<2, 8, KSU, KSU>(As + lr * KSU + lq * 8,
                             u1t + (size_t)(cb16 + lr) * KSU + lq * 8, acc);
    __syncthreads();

    {   // relu(GEMM1+b1+bfold) -> As[row][128..256) (aggr region, dead now)
        const int col = cb16 + lr;
        const float bv = b1[col];
        const float bfv = bf[col];
#pragma unroll
        for (int rt = 0; rt < 2; rt++) {
#pragma unroll
            for (int r = 0; r < 4; r++) {
                const int ml = rt * 16 + lq * 4 + r;
                float v = fmaxf(acc[rt][r] + bv + sF[ml] * bfv, 0.f);
                As[ml * KSU + 128 + col] = f2b(v);
            }
        }
    }
    __syncthreads();

    f32x4 acc2[2];
    acc2[0] = z4; acc2[1] = z4;
    gemm_1xR<2, 4, KSU, KS2>(As + lr * KSU + 128 + lq * 8,
                             u2t + (size_t)(cb16 + lr) * KS2 + lq * 8, acc2);
    __syncthreads();

    // MLP output + b2 into LN staging fp32 [32][132]
    {
        const int col = cb16 + lr;
        const float bv = b2[col];
#pragma unroll
        for (int rt = 0; rt < 2; rt++) {
#pragma unroll
            for (int r = 0; r < 4; r++) {
                const int ml = rt * 16 + lq * 4 + r;
                LNb[ml * 132 + col] = acc2[rt][r] + bv;
            }
        }
    }
    __syncthreads();

    // LayerNorm: 16 threads/row, 8 cols each; fp32 residual from hrv registers
    const int r = t >> 4, c0 = (t & 15) * 8;
    const int node = n0 + r;
    const bool valid = (node < N_NODES);
    float vbuf[8];
    if (valid) {
        float s = 0.f, ss = 0.f;
#pragma unroll
        for (int i = 0; i < 8; i++) {
            const float v = LNb[r * 132 + c0 + i] + hrv[i];
            vbuf[i] = v;
            s += v; ss += v * v;
        }
        s += __shfl_xor(s, 1); ss += __shfl_xor(ss, 1);
        s += __shfl_xor(s, 2); ss += __shfl_xor(ss, 2);
        s += __shfl_xor(s, 4); ss += __shfl_xor(ss, 4);
        s += __shfl_xor(s, 8); ss += __shfl_xor(ss, 8);
        const float mu = s * (1.0f / 128.0f);
        const float var = ss * (1.0f / 128.0f) - mu * mu;
        const float rs = rsqrtf(var + 1e-5f);
#pragma unroll
        for (int i = 0; i < 8; i++) {
            const int j = c0 + i;
            vbuf[i] = (vbuf[i] - mu) * rs * g[j] + bet[j];
        }
    }
    __syncthreads();   // all LNb reads done; re-use smemA as bf16 Ah[32][KS2]

    unsigned short* Ah = (unsigned short*)smemA;
    {
        unsigned short hb16[8];
#pragma unroll
        for (int i = 0; i < 8; i++) hb16[i] = valid ? f2b(vbuf[i]) : (unsigned short)0;
        uint4* arow = (uint4*)(Ah + (size_t)r * KS2 + c0);
        arow[0] = make_uint4(pk2(hb16[0], hb16[1]), pk2(hb16[2], hb16[3]),
                             pk2(hb16[4], hb16[5]), pk2(hb16[6], hb16[7]));
        if (mode == 2 && valid) {
            float4* drow = (float4*)(h_out + (size_t)node * 128 + c0);
            drow[0] = make_float4(vbuf[0], vbuf[1], vbuf[2], vbuf[3]);
            drow[1] = make_float4(vbuf[4], vbuf[5], vbuf[6], vbuf[7]);
        }
    }
    __syncthreads();

    if (mode == 1) {
        // head GEMM: wave -> rows (wv&1)*16..+15, cols (wv>>1)*32..+31
        const int m0 = (wv & 1) * 16;
        const int cblk = (wv >> 1) * 32;
        f32x4 hacc[1][2];
        hacc[0][0] = z4; hacc[0][1] = z4;
        gemm_2xR<1, 4, KS2, KS2>(Ah + (size_t)(m0 + lr) * KS2 + lq * 8,
                                 ht + (size_t)(cblk + lr) * KS2 + lq * 8, hacc);
#pragma unroll
        for (int ct = 0; ct < 2; ct++) {
            const int col = cblk + ct * 16 + lr;
            const float bv = hbias[col];
#pragma unroll
            for (int r2 = 0; r2 < 4; r2++) {
                const int node2 = n0 + m0 + lq * 4 + r2;
                if (node2 < N_NODES) out[(size_t)node2 * 128 + col] = hacc[0][ct][r2] + bv;
            }
        }
    } else {
        // next layer's node GEMM: 32 rows x 32 cols per wave (8 waves x 32 = 256)
        const int cbn = wv * 32;
        f32x4 accn[2][2];
#pragma unroll
        for (int i = 0; i < 2; i++) { accn[i][0] = z4; accn[i][1] = z4; }
        gemm_2xR<2, 4, KS2, KS2>(Ah + lr * KS2 + lq * 8,
                                 wabn + (size_t)(cbn + lr) * KS2 + lq * 8, accn);
#pragma unroll
        for (int ct = 0; ct < 2; ct++) {
            const int j = cbn + ct * 16 + lr;
            const float bias = (j < 128) ? b1n[j] : 0.f;
#pragma unroll
            for (int rt = 0; rt < 2; rt++) {
#pragma unroll
                for (int r2 = 0; r2 < 4; r2++) {
                    const int node2 = n0 + rt * 16 + lq * 4 + r2;
                    if (node2 < N_NODES) {
                        const float v = accn[rt][ct][r2] + bias;
                        if (j < 128) Tb[(size_t)node2 * 128 + j] = f2b(v);
                        else         Sb[(size_t)node2 * 128 + (j - 128)] = f2b(v);
                    }
                }
            }
        }
    }
}

extern "C" void kernel_launch(void* const* d_in, const int* in_sizes, int n_in,
                              void* d_out, int out_size, void* d_ws, size_t ws_size,
                              hipStream_t stream) {
    const float* x       = (const float*)d_in[0];
    const int*   ei      = (const int*)d_in[1];
    const float* ea      = (const float*)d_in[2];
    const float* encW    = (const float*)d_in[3];
    const float* encb    = (const float*)d_in[4];
    const float* encg    = (const float*)d_in[5];
    const float* encbeta = (const float*)d_in[6];
    const float* msgW1   = (const float*)d_in[7];
    const float* msgb1   = (const float*)d_in[8];
    const float* msgW2   = (const float*)d_in[9];
    const float* msgb2   = (const float*)d_in[10];
    const float* updW1   = (const float*)d_in[11];
    const float* updb1   = (const float*)d_in[12];
    const float* updW2   = (const float*)d_in[13];
    const float* updb2   = (const float*)d_in[14];
    const float* lng     = (const float*)d_in[15];
    const float* lnbeta  = (const float*)d_in[16];
    const float* headW   = (const float*)d_in[17];
    const float* headb   = (const float*)d_in[18];

    char* w = (char*)d_ws;
    size_t off = 0;
    auto nxt = [&](size_t bytes) -> void* {
        void* p = w + off;
        off = (off + bytes + 255) & ~(size_t)255;
        return p;
    };
    float*          h     = (float*)nxt((size_t)N_NODES * 128 * 4);
    float*          aggr  = (float*)nxt((size_t)N_NODES * 128 * 4);
    unsigned short* Tb    = (unsigned short*)nxt((size_t)N_NODES * 128 * 2);
    unsigned short* Sb    = (unsigned short*)nxt((size_t)N_NODES * 128 * 2);
    unsigned short* eabS  = (unsigned short*)nxt((size_t)N_EDGES * 16 * 2);
    unsigned int*   sST   = (unsigned int*)nxt((size_t)N_EDGES * 4);
    int*            hist  = (int*)nxt((size_t)N_NODES * 4);
    int*            incl  = (int*)nxt((size_t)N_NODES * 4);   // becomes cursor
    int*            blksum= (int*)nxt(256 * 4);
    unsigned short* wab   = (unsigned short*)nxt((size_t)NL * 256 * 136 * 2);
    unsigned short* w1cp  = (unsigned short*)nxt((size_t)NL * 128 * 32 * 2);
    unsigned short* u1t   = (unsigned short*)nxt((size_t)NL * 128 * KSU * 2);
    unsigned short* u2t   = (unsigned short*)nxt((size_t)NL * 128 * KS2 * 2);
    unsigned short* ht    = (unsigned short*)nxt((size_t)128 * KS2 * 2);
    float*          bfold = (float*)nxt((size_t)NL * 128 * 4);

    // permst (6.4 MB) aliases aggr (25.6 MB): permst's last use (gather_kernel)
    // strictly precedes aggr's first memset on the same stream.
    uint2*          permst = (uint2*)aggr;

    const int NBLK = (N_NODES + 255) / 256;   // 196
    const int NODEBLK = (N_NODES + 31) / 32;  // 1563
    const int PREP_N = NL * 256 * 136 + NL * 128 * 32 + NL * 128 * KSU
                     + NL * 128 * KS2 + 128 * KS2;

    hipMemsetAsync(hist, 0, (size_t)N_NODES * 4, stream);
    prep_kernel<<<(PREP_N + 255) / 256, 256, 0, stream>>>(msgW1, updW1, updW2, headW,
                                                          wab, w1cp, u1t, u2t, ht);
    prep2_kernel<<<NL * 128, 128, 0, stream>>>(msgW2, updW1, u1t);
    prep3_kernel<<<NL, 128, 0, stream>>>(msgb2, updW1, bfold);
    // fused encoder + layer-0 node GEMM (needs wab from prep_kernel)
    encnode_kernel<<<NODEBLK, 512, 0, stream>>>(x, encW, encb, encg, encbeta,
                                                wab, msgb1, h, Tb, Sb);
    hist_kernel<<<3125, 256, 0, stream>>>(ei + N_EDGES, hist);
    scan1_kernel<<<NBLK, 256, 0, stream>>>(hist, incl, blksum);
    scan2_kernel<<<1, 256, 0, stream>>>(blksum, NBLK);
    scan3_kernel<<<NBLK, 256, 0, stream>>>(incl, blksum, hist);
    scatterp_kernel<<<3125, 256, 0, stream>>>(ei, ei + N_EDGES, incl, permst);
    gather_kernel<<<3125, 256, 0, stream>>>(permst, ea, sST, eabS);

    for (int l = 0; l < NL; l++) {
        hipMemsetAsync(aggr, 0, (size_t)N_NODES * 128 * 4, stream);
        edge_kernel<<<12500, 256, 0, stream>>>(eabS, sST,
                                               w1cp + (size_t)l * 128 * 32,
                                               Tb, Sb, aggr);
        upd_kernel<<<NODEBLK, 512, 0, stream>>>(h, aggr, hist,
                                            u1t + (size_t)l * 128 * KSU,
                                            u2t + (size_t)l * 128 * KS2,
                                            updb1 + l * 128, bfold + l * 128,
                                            updb2 + l * 128,
                                            lng + l * 128, lnbeta + l * 128,
                                            h,
                                            wab + (size_t)(l + 1 < NL ? l + 1 : 0) * 256 * 136,
                                            msgb1 + (l + 1 < NL ? l + 1 : 0) * 128,
                                            Tb, Sb,
                                            ht, headb, (float*)d_out,
                                            (l == NL - 1) ? 1 : 2);
    }
}

// Round 14
// 478.127 us; speedup vs baseline: 1.0156x; 1.0156x over previous
//
#include <hip/hip_runtime.h>
#include <hip/hip_bf16.h>
#include <stdint.h>

#define N_NODES 50000
#define N_EDGES 800000
#define NL 2

// K strides (bf16 elements)
#define KS2 136   // 128-K GEMMs: 4 k-steps, stride 136
#define KSU 264   // upd GEMM1: K=256 (8 k-steps), stride 264
// edge_kernel fp32 LDS stride (dwords): 132 -> 528B rows, 16B-aligned (b128-capable).
// NOTE (R6 post-mortem): do NOT remap P2 gathers to 128B/row contiguous form —
// full-line random requests thrash L2 (aggr dirty-evictions: WRITE 31->118MB,
// dur 66->72us). The 32B-interleaved mapping below is the measured optimum.
// NOTE (R11 post-mortem): residual trunk MUST stay fp32 (bf16 residual -> absmax
// 0.06-0.125 vs threshold 0.09875; LN amplifies the rounding). h is fp32; the
// residual rides in registers between upd's staging and LN phases.
// NOTE (R13 post-mortem): XCD-chunked block swizzle on edge_kernel is a NO-OP
// (FETCH -1.6%, total regressed) — gather misses are dominated by random-source
// Sb reads + compulsory eabS stream, not Tb locality. Keep linear blockIdx.
#define ESTR 132

typedef __bf16 bf16x8 __attribute__((ext_vector_type(8)));
typedef float f32x4 __attribute__((ext_vector_type(4)));

__device__ __forceinline__ f32x4 mfma_bf16(uint4 a, uint4 b, f32x4 c) {
    return __builtin_amdgcn_mfma_f32_16x16x32_bf16(
        __builtin_bit_cast(bf16x8, a), __builtin_bit_cast(bf16x8, b), c, 0, 0, 0);
}

__device__ __forceinline__ unsigned short f2b(float f) {
    union { float f; unsigned u; } v; v.f = f;
    unsigned r = v.u + 0x7FFFu + ((v.u >> 16) & 1u);   // RNE
    return (unsigned short)(r >> 16);
}

__device__ __forceinline__ float b2f_lo(unsigned u) {
    union { unsigned u; float f; } v; v.u = u << 16; return v.f;
}
__device__ __forceinline__ float b2f_hi(unsigned u) {
    union { unsigned u; float f; } v; v.u = u & 0xFFFF0000u; return v.f;
}
__device__ __forceinline__ unsigned pk2(unsigned short a, unsigned short b) {
    return (unsigned)a | ((unsigned)b << 16);
}

// RT row-tiles x 1 col-tile per wave.
template<int RT, int KSTEPS, int ASTR, int BSTR>
__device__ __forceinline__ void gemm_1xR(const unsigned short* aLane,
                                         const unsigned short* bLane,
                                         f32x4 acc[RT]) {
#pragma unroll
    for (int kc = 0; kc < KSTEPS; kc++) {
        uint4 b0 = *(const uint4*)(bLane + kc * 32);
#pragma unroll
        for (int rt = 0; rt < RT; rt++) {
            uint4 a = *(const uint4*)(aLane + (size_t)rt * 16 * ASTR + kc * 32);
            acc[rt] = mfma_bf16(a, b0, acc[rt]);
        }
    }
}

// RT row-tiles x 2 col-tiles per wave.
template<int RT, int KSTEPS, int ASTR, int BSTR>
__device__ __forceinline__ void gemm_2xR(const unsigned short* aLane,
                                         const unsigned short* bLane,
                                         f32x4 acc[RT][2]) {
#pragma unroll
    for (int kc = 0; kc < KSTEPS; kc++) {
        uint4 b0 = *(const uint4*)(bLane + kc * 32);
        uint4 b1 = *(const uint4*)(bLane + (size_t)16 * BSTR + kc * 32);
#pragma unroll
        for (int rt = 0; rt < RT; rt++) {
            uint4 a = *(const uint4*)(aLane + (size_t)rt * 16 * ASTR + kc * 32);
            acc[rt][0] = mfma_bf16(a, b0, acc[rt][0]);
            acc[rt][1] = mfma_bf16(a, b1, acc[rt][1]);
        }
    }
}

// ---------------- weight prep ----------------
__global__ void prep_kernel(const float* __restrict__ mW1,
                            const float* __restrict__ uW1, const float* __restrict__ uW2,
                            const float* __restrict__ hW,
                            unsigned short* __restrict__ wab, unsigned short* __restrict__ w1cp,
                            unsigned short* __restrict__ u1t, unsigned short* __restrict__ u2t,
                            unsigned short* __restrict__ ht) {
    int i = blockIdx.x * 256 + threadIdx.x;
    const int SA = NL * 256 * 136;
    const int SC = NL * 128 * 32;
    const int SU = NL * 128 * KSU;
    const int S3 = NL * 128 * KS2;
    const int S4 = 128 * KS2;
    if (i < SA) {
        int l = i / (256 * 136), r = i % (256 * 136), j = r / 136, k = r % 136;
        float v = 0.f;
        if (k < 128)
            v = (j < 128) ? mW1[((size_t)l * 272 + k) * 128 + j]
                          : mW1[((size_t)l * 272 + 128 + k) * 128 + (j - 128)];
        wab[i] = f2b(v);
        return;
    }
    i -= SA;
    if (i < SC) {
        int l = i / (128 * 32), r = i % (128 * 32), j = r / 32, k = r % 32;
        w1cp[i] = (k < 16) ? f2b(mW1[((size_t)l * 272 + 256 + k) * 128 + j]) : (unsigned short)0;
        return;
    }
    i -= SC;
    if (i < SU) {
        int l = i / (128 * KSU), r = i % (128 * KSU), n = r / KSU, k = r % KSU;
        if (k < 128)       u1t[i] = f2b(uW1[((size_t)l * 256 + k) * 128 + n]);
        else if (k >= 256) u1t[i] = 0;
        return;
    }
    i -= SU;
    if (i < S3) {
        int l = i / (128 * KS2), r = i % (128 * KS2), n = r / KS2, k = r % KS2;
        u2t[i] = (k < 128) ? f2b(uW2[((size_t)l * 128 + k) * 128 + n]) : (unsigned short)0;
        return;
    }
    i -= S3;
    if (i < S4) {
        int n = i / KS2, k = i % KS2;
        ht[i] = (k < 128) ? f2b(hW[(size_t)k * 128 + n]) : (unsigned short)0;
    }
}

// ---------------- prep2: u1t[l][n][128+j] = bf16( sum_c W2[l][j][c] * U1[l][128+c][n] )
__global__ void prep2_kernel(const float* __restrict__ mW2, const float* __restrict__ uW1,
                             unsigned short* __restrict__ u1t) {
    __shared__ float w2row[128];
    const int l = blockIdx.x >> 7, j = blockIdx.x & 127;
    const int n = threadIdx.x;
    w2row[n] = mW2[((size_t)l * 128 + j) * 128 + n];
    __syncthreads();
    float s = 0.f;
#pragma unroll 8
    for (int c = 0; c < 128; c++)
        s += w2row[c] * uW1[((size_t)l * 256 + 128 + c) * 128 + n];
    u1t[(size_t)l * 128 * KSU + (size_t)n * KSU + 128 + j] = f2b(s);
}

// ---------------- prep3: bfold[l][n] = sum_c b2[l][c] * U1[l][128+c][n]
__global__ void prep3_kernel(const float* __restrict__ mb2, const float* __restrict__ uW1,
                             float* __restrict__ bfold) {
    const int l = blockIdx.x;
    const int n = threadIdx.x;
    float s = 0.f;
#pragma unroll 8
    for (int c = 0; c < 128; c++)
        s += mb2[l * 128 + c] * uW1[((size_t)l * 256 + 128 + c) * 128 + n];
    bfold[l * 128 + n] = s;
}

// ---------------- fused encoder + layer-0 node GEMM ----------------
// 32 nodes/block, 512 threads, 1563 blocks.
__global__ __launch_bounds__(512, 8) void encnode_kernel(
        const float* __restrict__ x, const float* __restrict__ W,
        const float* __restrict__ b, const float* __restrict__ g, const float* __restrict__ bet,
        const unsigned short* __restrict__ wab, const float* __restrict__ b1,
        float* __restrict__ h,
        unsigned short* __restrict__ Tb, unsigned short* __restrict__ Sb) {
    __shared__ __align__(16) unsigned short Ah[32 * KS2];   // 8704 B
    __shared__ float xs[32 * 33];                           // 4224 B
    __shared__ __align__(16) float Ws[32 * 128];            // 16384 B
    const int t = threadIdx.x;
    const int n0 = blockIdx.x * 32;

    {   // stage x: 16 threads/row, float2 each (row stride 33)
        const int m = t >> 4, q = t & 15;
        const int nd = n0 + m;
        float2 v = {0.f, 0.f};
        if (nd < N_NODES) v = *(const float2*)(x + (size_t)nd * 32 + q * 2);
        xs[m * 33 + q * 2 + 0] = v.x;
        xs[m * 33 + q * 2 + 1] = v.y;
    }
    {   // stage W [32][128] f32
        const float4* s = (const float4*)W;
        float4* d = (float4*)Ws;
        d[t * 2] = s[t * 2];
        d[t * 2 + 1] = s[t * 2 + 1];
    }
    __syncthreads();

    const int r = t >> 4, q16 = t & 15;
    const int node = n0 + r;
    const bool valid = (node < N_NODES);

    // Phase A: cols c = q16 + 16j, j<8
    float vbuf[8];
#pragma unroll
    for (int j = 0; j < 8; j++) vbuf[j] = b[q16 + 16 * j];
    for (int k = 0; k < 32; k++) {
        const float xv = xs[r * 33 + k];
#pragma unroll
        for (int j = 0; j < 8; j++)
            vbuf[j] += xv * Ws[k * 128 + q16 + 16 * j];
    }
#pragma unroll
    for (int j = 0; j < 8; j++) vbuf[j] = fmaxf(vbuf[j], 0.f);

    // Phase B: LN over row r (16 lanes/row); write h fp32 + Ah bf16
    {
        float s = 0.f, ss = 0.f;
#pragma unroll
        for (int j = 0; j < 8; j++) { s += vbuf[j]; ss += vbuf[j] * vbuf[j]; }
        s += __shfl_xor(s, 1); ss += __shfl_xor(ss, 1);
        s += __shfl_xor(s, 2); ss += __shfl_xor(ss, 2);
        s += __shfl_xor(s, 4); ss += __shfl_xor(ss, 4);
        s += __shfl_xor(s, 8); ss += __shfl_xor(ss, 8);
        const float mu = s * (1.0f / 128.0f);
        const float var = ss * (1.0f / 128.0f) - mu * mu;
        const float rs = rsqrtf(var + 1e-5f);
#pragma unroll
        for (int j = 0; j < 8; j++) {
            const int col = q16 + 16 * j;
            const float v = (vbuf[j] - mu) * rs * g[col] + bet[col];
            Ah[r * KS2 + col] = valid ? f2b(v) : (unsigned short)0;
            if (valid) h[(size_t)node * 128 + col] = v;
        }
    }
    __syncthreads();

    // Phase C: node l=0 GEMM epilogue (32 rows x 32 cols per wave)
    const int wv = t >> 6, lane = t & 63, lr = lane & 15, lq = lane >> 4;
    const int cbn = wv * 32;
    const f32x4 z4 = {0.f, 0.f, 0.f, 0.f};
    f32x4 accn[2][2];
#pragma unroll
    for (int i = 0; i < 2; i++) { accn[i][0] = z4; accn[i][1] = z4; }
    gemm_2xR<2, 4, KS2, KS2>(Ah + lr * KS2 + lq * 8,
                             wab + (size_t)(cbn + lr) * KS2 + lq * 8, accn);
#pragma unroll
    for (int ct = 0; ct < 2; ct++) {
        const int j = cbn + ct * 16 + lr;
        const float bias = (j < 128) ? b1[j] : 0.f;
#pragma unroll
        for (int rt = 0; rt < 2; rt++) {
#pragma unroll
            for (int r2 = 0; r2 < 4; r2++) {
                const int node2 = n0 + rt * 16 + lq * 4 + r2;
                if (node2 < N_NODES) {
                    const float v = accn[rt][ct][r2] + bias;
                    if (j < 128) Tb[(size_t)node2 * 128 + j] = f2b(v);
                    else         Sb[(size_t)node2 * 128 + (j - 128)] = f2b(v);
                }
            }
        }
    }
}

// ---------------- counting sort of edges by target ----------------
__global__ void hist_kernel(const int* __restrict__ tgt, int* __restrict__ hist) {
    int i = blockIdx.x * 256 + threadIdx.x;   // E = 3125*256 exact
    atomicAdd(hist + tgt[i], 1);
}

__global__ void scan1_kernel(const int* __restrict__ hist, int* __restrict__ incl,
                             int* __restrict__ blksum) {
    __shared__ int buf[256];
    const int t = threadIdx.x;
    const int i = blockIdx.x * 256 + t;
    int v = (i < N_NODES) ? hist[i] : 0;
    buf[t] = v; __syncthreads();
#pragma unroll
    for (int d = 1; d < 256; d <<= 1) {
        int x = (t >= d) ? buf[t - d] : 0;
        __syncthreads();
        buf[t] += x;
        __syncthreads();
    }
    if (i < N_NODES) incl[i] = buf[t];
    if (t == 255) blksum[blockIdx.x] = buf[255];
}

__global__ void scan2_kernel(int* __restrict__ blksum, int nblk) {
    __shared__ int buf[256];
    const int t = threadIdx.x;
    int v = (t < nblk) ? blksum[t] : 0;
    buf[t] = v; __syncthreads();
#pragma unroll
    for (int d = 1; d < 256; d <<= 1) {
        int x = (t >= d) ? buf[t - d] : 0;
        __syncthreads();
        buf[t] += x;
        __syncthreads();
    }
    if (t < nblk) blksum[t] = buf[t];
}

__global__ void scan3_kernel(int* __restrict__ incl, const int* __restrict__ blksum,
                             const int* __restrict__ hist) {
    const int i = blockIdx.x * 256 + threadIdx.x;
    if (i >= N_NODES) return;
    const int b = blockIdx.x;
    const int base = (b > 0) ? blksum[b - 1] : 0;
    incl[i] = incl[i] + base - hist[i];
}

// ---------------- sort step 1: 8B random scatter of {edge id, packed src|tgt} ------
__global__ void scatterp_kernel(const int* __restrict__ src, const int* __restrict__ tgt,
                                int* __restrict__ cursor, uint2* __restrict__ permst) {
    const int e = blockIdx.x * 256 + threadIdx.x;   // E exact
    const int tg = tgt[e];
    const int p = atomicAdd(cursor + tg, 1);
    permst[p] = make_uint2((unsigned)e, ((unsigned)src[e] << 16) | (unsigned)tg);
}

// ---------------- sort step 2: coalesced gather + bf16 convert --------------------
__global__ __launch_bounds__(256) void gather_kernel(
        const uint2* __restrict__ permst, const float* __restrict__ ea,
        unsigned int* __restrict__ sST, unsigned short* __restrict__ eabS) {
    const int p = blockIdx.x * 256 + threadIdx.x;   // E exact
    const uint2 v = permst[p];
    sST[p] = v.y;
    const float4* s = (const float4*)(ea + (size_t)v.x * 16);
    ushort4* d = (ushort4*)(eabS + (size_t)p * 16);
#pragma unroll
    for (int i = 0; i < 4; i++) {
        float4 f = s[i];
        d[i] = make_ushort4(f2b(f.x), f2b(f.y), f2b(f.z), f2b(f.w));
    }
}

// ---------------- edge kernel: relu(T[tgt]+S[src]+ea@W1c) + segmented sum ----------------
// 64 edges/block as two 32-edge half-tiles over one fp32 LDS buffer Es[32][ESTR=132]
// (17.4 KB LDS -> 8 blocks/CU). R5-measured optimum: 66us, 0 bank conflicts.
__global__ __launch_bounds__(256, 8) void edge_kernel(
        const unsigned short* __restrict__ eabS,
        const unsigned int* __restrict__ sST,
        const unsigned short* __restrict__ w1cp,
        const unsigned short* __restrict__ Tb, const unsigned short* __restrict__ Sb,
        float* __restrict__ aggr) {
    __shared__ __align__(16) float Es[32 * ESTR];
    __shared__ int sT[64];
    __shared__ int sS[64];

    const int t = threadIdx.x;
    const int e0 = blockIdx.x * 64;          // E = 12500*64 exact
    if (t < 64) {
        const unsigned v = sST[e0 + t];
        sT[t] = (int)(v & 0xFFFFu);
        sS[t] = (int)(v >> 16);
    }
    __syncthreads();                         // A: sT/sS visible

    const int wv = t >> 6, lane = t & 63, lr = lane & 15, lq = lane >> 4;
    const int rtw = (wv >> 1) * 16;          // row-tile base within half: 0 or 16
    const int cbw = (wv & 1) * 64;           // col-block base: 0 or 64
    const int m = t & 31, c8b = t >> 5;      // P2 mapping: edge-in-half, col chunk
    const f32x4 z4 = {0.f, 0.f, 0.f, 0.f};

    // boundary ballot (wave-uniform SGPR mask, same in all waves)
    unsigned long long bmask;
    {
        const int l = t & 63;
        const int a = sT[l];
        const int b = (l > 0) ? sT[l - 1] : a;
        bmask = __ballot(a != b);
    }

    // ---- issue half-0 gathers (consumed in P2 h0; hidden under P1 h0) ----
    uint4 t0a, t0b, s0a, s0b;
    {
        const unsigned short* Tr = Tb + (size_t)sT[m] * 128;
        const unsigned short* Sr = Sb + (size_t)sS[m] * 128;
        t0a = *(const uint4*)(Tr + c8b * 8);
        t0b = *(const uint4*)(Tr + c8b * 8 + 64);
        s0a = *(const uint4*)(Sr + c8b * 8);
        s0b = *(const uint4*)(Sr + c8b * 8 + 64);
    }

    float s = 0.f;                           // P3 running segment sum (t<128)
    bool first = true;                       // first flush -> atomic; interior -> store

    {   // ---- P1 h0 ----
        uint4 a = {0, 0, 0, 0};
        if (lq < 2)
            a = *(const uint4*)(eabS + (size_t)(e0 + rtw + lr) * 16 + lq * 8);
        f32x4 acc[4];
#pragma unroll
        for (int ct = 0; ct < 4; ct++) {
            uint4 b = *(const uint4*)(w1cp + (cbw + ct * 16 + lr) * 32 + lq * 8);
            acc[ct] = mfma_bf16(a, b, z4);
        }
#pragma unroll
        for (int ct = 0; ct < 4; ct++) {
            const int col = cbw + ct * 16 + lr;
#pragma unroll
            for (int r = 0; r < 4; r++)
                Es[(rtw + lq * 4 + r) * ESTR + col] = acc[ct][r];
        }
    }
    __syncthreads();                         // B

    uint4 t1a, t1b, s1a, s1b;
    {   // ---- P2 h0: consume prefetch, float4 RMW ----
        float* Erow = Es + m * ESTR;
        float4* EA = (float4*)(Erow + c8b * 8);
        float4* EB = (float4*)(Erow + c8b * 8 + 64);
        float4 ea0 = EA[0], ea1 = EA[1];
        ea0.x = fmaxf(ea0.x + b2f_lo(t0a.x) + b2f_lo(s0a.x), 0.f);
        ea0.y = fmaxf(ea0.y + b2f_hi(t0a.x) + b2f_hi(s0a.x), 0.f);
        ea0.z = fmaxf(ea0.z + b2f_lo(t0a.y) + b2f_lo(s0a.y), 0.f);
        ea0.w = fmaxf(ea0.w + b2f_hi(t0a.y) + b2f_hi(s0a.y), 0.f);
        ea1.x = fmaxf(ea1.x + b2f_lo(t0a.z) + b2f_lo(s0a.z), 0.f);
        ea1.y = fmaxf(ea1.y + b2f_hi(t0a.z) + b2f_hi(s0a.z), 0.f);
        ea1.z = fmaxf(ea1.z + b2f_lo(t0a.w) + b2f_lo(s0a.w), 0.f);
        ea1.w = fmaxf(ea1.w + b2f_hi(t0a.w) + b2f_hi(s0a.w), 0.f);
        EA[0] = ea0; EA[1] = ea1;
        float4 eb0 = EB[0], eb1 = EB[1];
        eb0.x = fmaxf(eb0.x + b2f_lo(t0b.x) + b2f_lo(s0b.x), 0.f);
        eb0.y = fmaxf(eb0.y + b2f_hi(t0b.x) + b2f_hi(s0b.x), 0.f);
        eb0.z = fmaxf(eb0.z + b2f_lo(t0b.y) + b2f_lo(s0b.y), 0.f);
        eb0.w = fmaxf(eb0.w + b2f_hi(t0b.y) + b2f_hi(s0b.y), 0.f);
        eb1.x = fmaxf(eb1.x + b2f_lo(t0b.z) + b2f_lo(s0b.z), 0.f);
        eb1.y = fmaxf(eb1.y + b2f_hi(t0b.z) + b2f_hi(s0b.z), 0.f);
        eb1.z = fmaxf(eb1.z + b2f_lo(t0b.w) + b2f_lo(s0b.w), 0.f);
        eb1.w = fmaxf(eb1.w + b2f_hi(t0b.w) + b2f_hi(s0b.w), 0.f);
        EB[0] = eb0; EB[1] = eb1;

        // ---- issue half-1 gathers (consumed in P2 h1; hidden under P3 h0 + P1 h1)
        const unsigned short* Tr = Tb + (size_t)sT[32 + m] * 128;
        const unsigned short* Sr = Sb + (size_t)sS[32 + m] * 128;
        t1a = *(const uint4*)(Tr + c8b * 8);
        t1b = *(const uint4*)(Tr + c8b * 8 + 64);
        s1a = *(const uint4*)(Sr + c8b * 8);
        s1b = *(const uint4*)(Sr + c8b * 8 + 64);
    }
    __syncthreads();                         // C

    if (t < 128) {   // ---- P3 h0: col c = t, rows 0..31, batched loads ----
        const int c = t;
        const unsigned mh = (unsigned)bmask;
#pragma unroll
        for (int i8 = 0; i8 < 4; i8++) {
            float v[8];
#pragma unroll
            for (int j = 0; j < 8; j++) v[j] = Es[(i8 * 8 + j) * ESTR + c];
#pragma unroll
            for (int j = 0; j < 8; j++) {
                const int i = i8 * 8 + j;
                if (mh & (1u << i)) {        // wave-uniform scalar branch
                    float* dst = aggr + (size_t)sT[i - 1] * 128 + c;
                    if (first) { atomicAdd(dst, s); first = false; }
                    else       { *dst = s; }
                    s = 0.f;
                }
                s += v[j];
            }
        }
    }
    __syncthreads();                         // D: Es free for h1

    {   // ---- P1 h1 ----
        uint4 a = {0, 0, 0, 0};
        if (lq < 2)
            a = *(const uint4*)(eabS + (size_t)(e0 + 32 + rtw + lr) * 16 + lq * 8);
        f32x4 acc[4];
#pragma unroll
        for (int ct = 0; ct < 4; ct++) {
            uint4 b = *(const uint4*)(w1cp + (cbw + ct * 16 + lr) * 32 + lq * 8);
            acc[ct] = mfma_bf16(a, b, z4);
        }
#pragma unroll
        for (int ct = 0; ct < 4; ct++) {
            const int col = cbw + ct * 16 + lr;
#pragma unroll
            for (int r = 0; r < 4; r++)
                Es[(rtw + lq * 4 + r) * ESTR + col] = acc[ct][r];
        }
    }
    __syncthreads();                         // E

    {   // ---- P2 h1 ----
        float* Erow = Es + m * ESTR;
        float4* EA = (float4*)(Erow + c8b * 8);
        float4* EB = (float4*)(Erow + c8b * 8 + 64);
        float4 ea0 = EA[0], ea1 = EA[1];
        ea0.x = fmaxf(ea0.x + b2f_lo(t1a.x) + b2f_lo(s1a.x), 0.f);
        ea0.y = fmaxf(ea0.y + b2f_hi(t1a.x) + b2f_hi(s1a.x), 0.f);
        ea0.z = fmaxf(ea0.z + b2f_lo(t1a.y) + b2f_lo(s1a.y), 0.f);
        ea0.w = fmaxf(ea0.w + b2f_hi(t1a.y) + b2f_hi(s1a.y), 0.f);
        ea1.x = fmaxf(ea1.x + b2f_lo(t1a.z) + b2f_lo(s1a.z), 0.f);
        ea1.y = fmaxf(ea1.y + b2f_hi(t1a.z) + b2f_hi(s1a.z), 0.f);
        ea1.z = fmaxf(ea1.z + b2f_lo(t1a.w) + b2f_lo(s1a.w), 0.f);
        ea1.w = fmaxf(ea1.w + b2f_hi(t1a.w) + b2f_hi(s1a.w), 0.f);
        EA[0] = ea0; EA[1] = ea1;
        float4 eb0 = EB[0], eb1 = EB[1];
        eb0.x = fmaxf(eb0.x + b2f_lo(t1b.x) + b2f_lo(s1b.x), 0.f);
        eb0.y = fmaxf(eb0.y + b2f_hi(t1b.x) + b2f_hi(s1b.x), 0.f);
        eb0.z = fmaxf(eb0.z + b2f_lo(t1b.y) + b2f_lo(s1b.y), 0.f);
        eb0.w = fmaxf(eb0.w + b2f_hi(t1b.y) + b2f_hi(s1b.y), 0.f);
        eb1.x = fmaxf(eb1.x + b2f_lo(t1b.z) + b2f_lo(s1b.z), 0.f);
        eb1.y = fmaxf(eb1.y + b2f_hi(t1b.z) + b2f_hi(s1b.z), 0.f);
        eb1.z = fmaxf(eb1.z + b2f_lo(t1b.w) + b2f_lo(s1b.w), 0.f);
        eb1.w = fmaxf(eb1.w + b2f_hi(t1b.w) + b2f_hi(s1b.w), 0.f);
        EB[0] = eb0; EB[1] = eb1;
    }
    __syncthreads();                         // F

    if (t < 128) {   // ---- P3 h1: rows 32..63 ----
        const int c = t;
        const unsigned mh = (unsigned)(bmask >> 32);
#pragma unroll
        for (int i8 = 0; i8 < 4; i8++) {
            float v[8];
#pragma unroll
            for (int j = 0; j < 8; j++) v[j] = Es[(i8 * 8 + j) * ESTR + c];
#pragma unroll
            for (int j = 0; j < 8; j++) {
                const int i = i8 * 8 + j;
                if (mh & (1u << i)) {
                    float* dst = aggr + (size_t)sT[32 + i - 1] * 128 + c;
                    if (first) { atomicAdd(dst, s); first = false; }
                    else       { *dst = s; }
                    s = 0.f;
                }
                s += v[j];
            }
        }
        atomicAdd(aggr + (size_t)sT[63] * 128 + c, s);   // may span blocks
    }
}

// ---------------- update MLP + residual(fp32, register-carried) + LN + epilogue ----
// 32 nodes/block, 512 threads, 1563 blocks. The fp32 residual rides in hrv[8]
// registers (staging thread slice == LN thread slice).
// mode==2 (layer 0): epilogue = next layer's node GEMM + h fp32 write-back.
// mode==1 (last layer): epilogue = head GEMM -> out.
__global__ __launch_bounds__(512, 8) void upd_kernel(
        const float* __restrict__ h_in,
        const float* __restrict__ aggr, const int* __restrict__ hist,
        const unsigned short* __restrict__ u1t, const unsigned short* __restrict__ u2t,
        const float* __restrict__ b1, const float* __restrict__ bf,
        const float* __restrict__ b2,
        const float* __restrict__ g, const float* __restrict__ bet,
        float* __restrict__ h_out,
        const unsigned short* __restrict__ wabn, const float* __restrict__ b1n,
        unsigned short* __restrict__ Tb, unsigned short* __restrict__ Sb,
        const unsigned short* __restrict__ ht, const float* __restrict__ hbias,
        float* __restrict__ out, const int mode) {
    __shared__ __align__(16) char smemA[32 * KSU * 2];   // 16896 B
    __shared__ float sF[32];
    unsigned short* As = (unsigned short*)smemA;
    float* LNb = (float*)smemA;                          // [32][132] fp32, same span

    const int t = threadIdx.x;
    const int n0 = blockIdx.x * 32;
    float hrv[8];                            // fp32 residual, staging -> LN phase
#pragma unroll
    for (int i = 0; i < 8; i++) hrv[i] = 0.f;
    {
        const int m = t >> 4, q = t & 15;    // 16 threads per row
        const int node = n0 + m;
        unsigned short* row = As + m * KSU;
        if (node < N_NODES) {
            const float4* ph = (const float4*)(h_in + (size_t)node * 128 + q * 8);
            const float4 h0 = ph[0], h1 = ph[1];
            hrv[0] = h0.x; hrv[1] = h0.y; hrv[2] = h0.z; hrv[3] = h0.w;
            hrv[4] = h1.x; hrv[5] = h1.y; hrv[6] = h1.z; hrv[7] = h1.w;
            ((uint4*)(row + q * 8))[0] =
                make_uint4(pk2(f2b(hrv[0]), f2b(hrv[1])), pk2(f2b(hrv[2]), f2b(hrv[3])),
                           pk2(f2b(hrv[4]), f2b(hrv[5])), pk2(f2b(hrv[6]), f2b(hrv[7])));
            const int cntv = hist[node];
            if (q == 0) sF[m] = (cntv > 0) ? 1.f : 0.f;
            const float rden = 1.0f / fmaxf((float)cntv, 1.0f);
            const float4* pa = (const float4*)(aggr + (size_t)node * 128 + q * 8);
            ushort4* d1 = (ushort4*)(row + 128 + q * 8);
#pragma unroll
            for (int i = 0; i < 2; i++) {
                float4 v = pa[i];
                d1[i] = make_ushort4(f2b(v.x * rden), f2b(v.y * rden),
                                     f2b(v.z * rden), f2b(v.w * rden));
            }
            if (q == 0) { uint4 z{0, 0, 0, 0}; ((uint4*)(row + 256))[0] = z; }
        } else {
            if (q == 0) sF[m] = 0.f;
            uint4 z{0, 0, 0, 0};
            uint4* d = (uint4*)row;
            for (int i = q; i < 33; i += 16) d[i] = z;
        }
    }
    __syncthreads();

    const int wv = t >> 6, lane = t & 63, lr = lane & 15, lq = lane >> 4;
    const int cb16 = wv * 16;                // 16 cols per wave (8 waves x 16 = 128)
    const f32x4 z4 = {0.f, 0.f, 0.f, 0.f};

    f32x4 acc[2];
    acc[0] = z4; acc[1] = z4;
    gemm_1xR<2, 8, KSU, KSU>(As + lr * KSU + lq * 8,
                             u1t + (size_t)(cb16 + lr) * KSU + lq * 8, acc);
    __syncthreads();

    {   // relu(GEMM1+b1+bfold) -> As[row][128..256) (aggr region, dead now)
        const int col = cb16 + lr;
        const float bv = b1[col];
        const float bfv = bf[col];
#pragma unroll
        for (int rt = 0; rt < 2; rt++) {
#pragma unroll
            for (int r = 0; r < 4; r++) {
                const int ml = rt * 16 + lq * 4 + r;
                float v = fmaxf(acc[rt][r] + bv + sF[ml] * bfv, 0.f);
                As[ml * KSU + 128 + col] = f2b(v);
            }
        }
    }
    __syncthreads();

    f32x4 acc2[2];
    acc2[0] = z4; acc2[1] = z4;
    gemm_1xR<2, 4, KSU, KS2>(As + lr * KSU + 128 + lq * 8,
                             u2t + (size_t)(cb16 + lr) * KS2 + lq * 8, acc2);
    __syncthreads();

    // MLP output + b2 into LN staging fp32 [32][132]
    {
        const int col = cb16 + lr;
        const float bv = b2[col];
#pragma unroll
        for (int rt = 0; rt < 2; rt++) {
#pragma unroll
            for (int r = 0; r < 4; r++) {
                const int ml = rt * 16 + lq * 4 + r;
                LNb[ml * 132 + col] = acc2[rt][r] + bv;
            }
        }
    }
    __syncthreads();

    // LayerNorm: 16 threads/row, 8 cols each; fp32 residual from hrv registers
    const int r = t >> 4, c0 = (t & 15) * 8;
    const int node = n0 + r;
    const bool valid = (node < N_NODES);
    float vbuf[8];
    if (valid) {
        float s = 0.f, ss = 0.f;
#pragma unroll
        for (int i = 0; i < 8; i++) {
            const float v = LNb[r * 132 + c0 + i] + hrv[i];
            vbuf[i] = v;
            s += v; ss += v * v;
        }
        s += __shfl_xor(s, 1); ss += __shfl_xor(ss, 1);
        s += __shfl_xor(s, 2); ss += __shfl_xor(ss, 2);
        s += __shfl_xor(s, 4); ss += __shfl_xor(ss, 4);
        s += __shfl_xor(s, 8); ss += __shfl_xor(ss, 8);
        const float mu = s * (1.0f / 128.0f);
        const float var = ss * (1.0f / 128.0f) - mu * mu;
        const float rs = rsqrtf(var + 1e-5f);
#pragma unroll
        for (int i = 0; i < 8; i++) {
            const int j = c0 + i;
            vbuf[i] = (vbuf[i] - mu) * rs * g[j] + bet[j];
        }
    }
    __syncthreads();   // all LNb reads done; re-use smemA as bf16 Ah[32][KS2]

    unsigned short* Ah = (unsigned short*)smemA;
    {
        unsigned short hb16[8];
#pragma unroll
        for (int i = 0; i < 8; i++) hb16[i] = valid ? f2b(vbuf[i]) : (unsigned short)0;
        uint4* arow = (uint4*)(Ah + (size_t)r * KS2 + c0);
        arow[0] = make_uint4(pk2(hb16[0], hb16[1]), pk2(hb16[2], hb16[3]),
                             pk2(hb16[4], hb16[5]), pk2(hb16[6], hb16[7]));
        if (mode == 2 && valid) {
            float4* drow = (float4*)(h_out + (size_t)node * 128 + c0);
            drow[0] = make_float4(vbuf[0], vbuf[1], vbuf[2], vbuf[3]);
            drow[1] = make_float4(vbuf[4], vbuf[5], vbuf[6], vbuf[7]);
        }
    }
    __syncthreads();

    if (mode == 1) {
        // head GEMM: wave -> rows (wv&1)*16..+15, cols (wv>>1)*32..+31
        const int m0 = (wv & 1) * 16;
        const int cblk = (wv >> 1) * 32;
        f32x4 hacc[1][2];
        hacc[0][0] = z4; hacc[0][1] = z4;
        gemm_2xR<1, 4, KS2, KS2>(Ah + (size_t)(m0 + lr) * KS2 + lq * 8,
                                 ht + (size_t)(cblk + lr) * KS2 + lq * 8, hacc);
#pragma unroll
        for (int ct = 0; ct < 2; ct++) {
            const int col = cblk + ct * 16 + lr;
            const float bv = hbias[col];
#pragma unroll
            for (int r2 = 0; r2 < 4; r2++) {
                const int node2 = n0 + m0 + lq * 4 + r2;
                if (node2 < N_NODES) out[(size_t)node2 * 128 + col] = hacc[0][ct][r2] + bv;
            }
        }
    } else {
        // next layer's node GEMM: 32 rows x 32 cols per wave (8 waves x 32 = 256)
        const int cbn = wv * 32;
        f32x4 accn[2][2];
#pragma unroll
        for (int i = 0; i < 2; i++) { accn[i][0] = z4; accn[i][1] = z4; }
        gemm_2xR<2, 4, KS2, KS2>(Ah + lr * KS2 + lq * 8,
                                 wabn + (size_t)(cbn + lr) * KS2 + lq * 8, accn);
#pragma unroll
        for (int ct = 0; ct < 2; ct++) {
            const int j = cbn + ct * 16 + lr;
            const float bias = (j < 128) ? b1n[j] : 0.f;
#pragma unroll
            for (int rt = 0; rt < 2; rt++) {
#pragma unroll
                for (int r2 = 0; r2 < 4; r2++) {
                    const int node2 = n0 + rt * 16 + lq * 4 + r2;
                    if (node2 < N_NODES) {
                        const float v = accn[rt][ct][r2] + bias;
                        if (j < 128) Tb[(size_t)node2 * 128 + j] = f2b(v);
                        else         Sb[(size_t)node2 * 128 + (j - 128)] = f2b(v);
                    }
                }
            }
        }
    }
}

extern "C" void kernel_launch(void* const* d_in, const int* in_sizes, int n_in,
                              void* d_out, int out_size, void* d_ws, size_t ws_size,
                              hipStream_t stream) {
    const float* x       = (const float*)d_in[0];
    const int*   ei      = (const int*)d_in[1];
    const float* ea      = (const float*)d_in[2];
    const float* encW    = (const float*)d_in[3];
    const float* encb    = (const float*)d_in[4];
    const float* encg    = (const float*)d_in[5];
    const float* encbeta = (const float*)d_in[6];
    const float* msgW1   = (const float*)d_in[7];
    const float* msgb1   = (const float*)d_in[8];
    const float* msgW2   = (const float*)d_in[9];
    const float* msgb2   = (const float*)d_in[10];
    const float* updW1   = (const float*)d_in[11];
    const float* updb1   = (const float*)d_in[12];
    const float* updW2   = (const float*)d_in[13];
    const float* updb2   = (const float*)d_in[14];
    const float* lng     = (const float*)d_in[15];
    const float* lnbeta  = (const float*)d_in[16];
    const float* headW   = (const float*)d_in[17];
    const float* headb   = (const float*)d_in[18];

    char* w = (char*)d_ws;
    size_t off = 0;
    auto nxt = [&](size_t bytes) -> void* {
        void* p = w + off;
        off = (off + bytes + 255) & ~(size_t)255;
        return p;
    };
    float*          h     = (float*)nxt((size_t)N_NODES * 128 * 4);
    float*          aggr  = (float*)nxt((size_t)N_NODES * 128 * 4);
    unsigned short* Tb    = (unsigned short*)nxt((size_t)N_NODES * 128 * 2);
    unsigned short* Sb    = (unsigned short*)nxt((size_t)N_NODES * 128 * 2);
    unsigned short* eabS  = (unsigned short*)nxt((size_t)N_EDGES * 16 * 2);
    unsigned int*   sST   = (unsigned int*)nxt((size_t)N_EDGES * 4);
    int*            hist  = (int*)nxt((size_t)N_NODES * 4);
    int*            incl  = (int*)nxt((size_t)N_NODES * 4);   // becomes cursor
    int*            blksum= (int*)nxt(256 * 4);
    unsigned short* wab   = (unsigned short*)nxt((size_t)NL * 256 * 136 * 2);
    unsigned short* w1cp  = (unsigned short*)nxt((size_t)NL * 128 * 32 * 2);
    unsigned short* u1t   = (unsigned short*)nxt((size_t)NL * 128 * KSU * 2);
    unsigned short* u2t   = (unsigned short*)nxt((size_t)NL * 128 * KS2 * 2);
    unsigned short* ht    = (unsigned short*)nxt((size_t)128 * KS2 * 2);
    float*          bfold = (float*)nxt((size_t)NL * 128 * 4);

    // permst (6.4 MB) aliases aggr (25.6 MB): permst's last use (gather_kernel)
    // strictly precedes aggr's first memset on the same stream.
    uint2*          permst = (uint2*)aggr;

    const int NBLK = (N_NODES + 255) / 256;   // 196
    const int NODEBLK = (N_NODES + 31) / 32;  // 1563
    const int PREP_N = NL * 256 * 136 + NL * 128 * 32 + NL * 128 * KSU
                     + NL * 128 * KS2 + 128 * KS2;

    hipMemsetAsync(hist, 0, (size_t)N_NODES * 4, stream);
    prep_kernel<<<(PREP_N + 255) / 256, 256, 0, stream>>>(msgW1, updW1, updW2, headW,
                                                          wab, w1cp, u1t, u2t, ht);
    prep2_kernel<<<NL * 128, 128, 0, stream>>>(msgW2, updW1, u1t);
    prep3_kernel<<<NL, 128, 0, stream>>>(msgb2, updW1, bfold);
    // fused encoder + layer-0 node GEMM (needs wab from prep_kernel)
    encnode_kernel<<<NODEBLK, 512, 0, stream>>>(x, encW, encb, encg, encbeta,
                                                wab, msgb1, h, Tb, Sb);
    hist_kernel<<<3125, 256, 0, stream>>>(ei + N_EDGES, hist);
    scan1_kernel<<<NBLK, 256, 0, stream>>>(hist, incl, blksum);
    scan2_kernel<<<1, 256, 0, stream>>>(blksum, NBLK);
    scan3_kernel<<<NBLK, 256, 0, stream>>>(incl, blksum, hist);
    scatterp_kernel<<<3125, 256, 0, stream>>>(ei, ei + N_EDGES, incl, permst);
    gather_kernel<<<3125, 256, 0, stream>>>(permst, ea, sST, eabS);

    for (int l = 0; l < NL; l++) {
        hipMemsetAsync(aggr, 0, (size_t)N_NODES * 128 * 4, stream);
        edge_kernel<<<12500, 256, 0, stream>>>(eabS, sST,
                                               w1cp + (size_t)l * 128 * 32,
                                               Tb, Sb, aggr);
        upd_kernel<<<NODEBLK, 512, 0, stream>>>(h, aggr, hist,
                                            u1t + (size_t)l * 128 * KSU,
                                            u2t + (size_t)l * 128 * KS2,
                                            updb1 + l * 128, bfold + l * 128,
                                            updb2 + l * 128,
                                            lng + l * 128, lnbeta + l * 128,
                                            h,
                                            wab + (size_t)(l + 1 < NL ? l + 1 : 0) * 256 * 136,
                                            msgb1 + (l + 1 < NL ? l + 1 : 0) * 128,
                                            Tb, Sb,
                                            ht, headb, (float*)d_out,
                                            (l == NL - 1) ? 1 : 2);
    }
}